// Round 9
// baseline (682.979 us; speedup 1.0000x reference)
//
#include <hip/hip_runtime.h>
#include <hip/hip_bf16.h>
#include <math.h>

#define N_ENVS   4096
#define N_AGENTS 64
#define OBS_DIM  256
#define HIDDEN   512
#define HEADK    32
#define BROWS    128   // rows per block = 64 envs x 2 agents

typedef __attribute__((ext_vector_type(8))) short bf16x8;
typedef __attribute__((ext_vector_type(8))) unsigned short u16x8;
typedef __attribute__((ext_vector_type(4))) float f32x4;

static __device__ __forceinline__ unsigned short f2bf(float x) {
    union { float f; unsigned int u; } v; v.f = x;
    unsigned int r = (v.u + 0x7FFFu + ((v.u >> 16) & 1u)) >> 16;
    return (unsigned short)r;
}

// MFMA with the accumulator PINNED to AGPRs ("a" constraint). Round 7/8
// evidence: with builtin intrinsics at 1024 thr (128-reg budget), the
// allocator kept acc on the arch-VGPR side and spilled ~30 regs/thread
// (255MB scratch, immovable by any source-level loop-form change). Pinning
// C/D to AGPR frees the full 64 arch VGPRs for loop state.
static __device__ __forceinline__ f32x4 mfma16(bf16x8 a, bf16x8 b, f32x4 c) {
    asm("v_mfma_f32_16x16x32_bf16 %0, %1, %2, %0" : "+a"(c) : "v"(a), "v"(b));
    return c;
}

// Convert + transpose weights to bf16, N-major (so B-fragments are 16B contiguous).
__global__ void prep_weights_kernel(const float* __restrict__ W1,
                                    const float* __restrict__ W2,
                                    const float* __restrict__ HW1,
                                    unsigned short* __restrict__ W1T,
                                    unsigned short* __restrict__ W2T,
                                    unsigned short* __restrict__ HW1T) {
    int id = blockIdx.x * 256 + threadIdx.x;
    if (id < 131072) {                      // W1 [256][512] -> W1T [512][256]
        int k = id >> 9, n = id & 511;
        W1T[n * 256 + k] = f2bf(W1[id]);
    } else if (id < 131072 + 262144) {      // W2 [512][512] -> W2T [512][512]
        int t = id - 131072;
        int k = t >> 9, n = t & 511;
        W2T[n * 512 + k] = f2bf(W2[t]);
    } else if (id < 131072 + 262144 + 1048576) {  // HW1 [64][512][32] -> HW1T [64][32][512]
        int t = id - (131072 + 262144);
        int ag = t >> 14;
        int rem = t & 16383;
        int hh = rem >> 5, c = rem & 31;
        HW1T[((ag << 5) + c) * 512 + hh] = f2bf(HW1[t]);
    }
}

// Fused: obs -> (GEMM1 relu) -> (GEMM2 relu) -> per-agent head1 relu -> head2 sigmoid.
// Block = 64 envs x 2 agents = 128 rows. 1024 threads = 16 waves; each wave
// owns all 128 rows x 32 cols -> acc[8][2] = 64 regs, now pinned to AGPRs.
// Arch-VGPR demand: bcur/bnxt 16 + a-frags 8 + addressing ~15 < 64 available.
__launch_bounds__(1024, 1)
__global__ void fused_mlp_kernel(const float* __restrict__ obs,
                                 const float* __restrict__ b1,
                                 const float* __restrict__ b2,
                                 const float* __restrict__ Hb1,
                                 const float* __restrict__ HW2,
                                 const float* __restrict__ Hb2,
                                 const unsigned short* __restrict__ W1T,
                                 const unsigned short* __restrict__ W2T,
                                 const unsigned short* __restrict__ HW1T,
                                 float* __restrict__ out) {
    __shared__ unsigned short buf[BROWS * 512];  // 128 KB: obs(first half), h, feat
    __shared__ float gpart[BROWS * 36];          // 18 KB : g (pad 36)

    const int tid  = threadIdx.x;
    const int lane = tid & 63;
    const int wid  = tid >> 6;   // 0..15 : col group (32 cols each)
    const int l15  = lane & 15;
    const int lk   = lane >> 4;  // 0..3
    const int e0   = blockIdx.x * 64;
    const int ap   = blockIdx.y; // agent pair: agents 2ap, 2ap+1

    const f32x4 fzero = {0.f, 0.f, 0.f, 0.f};

    // ------------- stage obs tile [128][256] bf16 swizzled; row = j*64 + e -------------
    // 32-bit addressing (max float index 67M < 2^32), unroll 1: low reg pressure.
    {
        const unsigned fbase = ((unsigned)e0 * 64u + 2u * (unsigned)ap) * 256u;
        #pragma unroll 1
        for (int g = 0; g < 4; ++g) {
            unsigned gi  = (unsigned)tid + 1024u * g;   // 4096 groups of 8 floats
            unsigned row = gi >> 5;                     // 0..127
            unsigned kg  = (gi & 31u) << 3;
            unsigned fidx = fbase + (row & 63u) * 16384u + (row >> 6) * 256u + kg;
            const float4* p = reinterpret_cast<const float4*>(obs + fidx);
            float4 v0 = p[0], v1 = p[1];
            u16x8 w;
            w[0] = f2bf(v0.x); w[1] = f2bf(v0.y); w[2] = f2bf(v0.z); w[3] = f2bf(v0.w);
            w[4] = f2bf(v1.x); w[5] = f2bf(v1.y); w[6] = f2bf(v1.z); w[7] = f2bf(v1.w);
            unsigned byt = (row * 512u + kg * 2u) ^ ((row & 7u) << 4);
            *reinterpret_cast<u16x8*>(&buf[byt >> 1]) = w;
        }
    }
    __syncthreads();

    // ---------------- GEMM1: h = relu(obs @ W1 + b1), K=256 ----------------
    f32x4 acc[8][2];   // [mi rows 0..127][ni cols] -- AGPR-pinned via mfma16
    #pragma unroll
    for (int i = 0; i < 8; ++i)
        #pragma unroll
        for (int j = 0; j < 2; ++j) acc[i][j] = fzero;

    {
        const unsigned short* bbase = W1T + (size_t)(wid * 32 + l15) * 256 + lk * 8;
        bf16x8 bcur[2];
        #pragma unroll
        for (int ni = 0; ni < 2; ++ni)
            bcur[ni] = *reinterpret_cast<const bf16x8*>(bbase + ni * 16 * 256);
        #pragma unroll 1
        for (int ks = 0; ks < 8; ++ks) {
            bf16x8 bnxt[2];
            const int kn = (ks < 7 ? ks + 1 : 7);
            #pragma unroll
            for (int ni = 0; ni < 2; ++ni)
                bnxt[ni] = *reinterpret_cast<const bf16x8*>(bbase + ni * 16 * 256 + kn * 32);
            const int kk = ks * 32 + lk * 8;
            #pragma unroll
            for (int mi = 0; mi < 8; mi += 2) {
                int r0 = mi * 16 + l15, r1 = r0 + 16;
                bf16x8 a0 = *reinterpret_cast<const bf16x8*>(&buf[((r0 * 512 + kk * 2) ^ ((r0 & 7) << 4)) >> 1]);
                bf16x8 a1 = *reinterpret_cast<const bf16x8*>(&buf[((r1 * 512 + kk * 2) ^ ((r1 & 7) << 4)) >> 1]);
                #pragma unroll
                for (int ni = 0; ni < 2; ++ni) {
                    acc[mi][ni]     = mfma16(a0, bcur[ni], acc[mi][ni]);
                    acc[mi + 1][ni] = mfma16(a1, bcur[ni], acc[mi + 1][ni]);
                }
            }
            bcur[0] = bnxt[0]; bcur[1] = bnxt[1];
        }
    }
    __syncthreads();   // all obs reads done -> safe to overwrite buf with h

    // epilogue: +b1, relu, write h into buf ([128][512] swizzled)
    #pragma unroll
    for (int ni = 0; ni < 2; ++ni) {
        int col = wid * 32 + ni * 16 + l15;
        float bias = b1[col];
        #pragma unroll
        for (int mi = 0; mi < 8; ++mi)
            #pragma unroll
            for (int r = 0; r < 4; ++r) {
                int row = mi * 16 + lk * 4 + r;
                float v = acc[mi][ni][r] + bias;
                v = v > 0.f ? v : 0.f;
                int byt = (row * 1024 + col * 2) ^ ((row & 7) << 4);
                buf[byt >> 1] = f2bf(v);
            }
    }
    __syncthreads();

    // ---------------- GEMM2: feat = relu(h @ W2 + b2), K=512 ----------------
    #pragma unroll
    for (int i = 0; i < 8; ++i)
        #pragma unroll
        for (int j = 0; j < 2; ++j) acc[i][j] = fzero;

    {
        const unsigned short* bbase = W2T + (size_t)(wid * 32 + l15) * 512 + lk * 8;
        bf16x8 bcur[2];
        #pragma unroll
        for (int ni = 0; ni < 2; ++ni)
            bcur[ni] = *reinterpret_cast<const bf16x8*>(bbase + ni * 16 * 512);
        #pragma unroll 1
        for (int ks = 0; ks < 16; ++ks) {
            bf16x8 bnxt[2];
            const int kn = (ks < 15 ? ks + 1 : 15);
            #pragma unroll
            for (int ni = 0; ni < 2; ++ni)
                bnxt[ni] = *reinterpret_cast<const bf16x8*>(bbase + ni * 16 * 512 + kn * 32);
            const int kk = ks * 32 + lk * 8;
            #pragma unroll
            for (int mi = 0; mi < 8; mi += 2) {
                int r0 = mi * 16 + l15, r1 = r0 + 16;
                bf16x8 a0 = *reinterpret_cast<const bf16x8*>(&buf[((r0 * 1024 + kk * 2) ^ ((r0 & 7) << 4)) >> 1]);
                bf16x8 a1 = *reinterpret_cast<const bf16x8*>(&buf[((r1 * 1024 + kk * 2) ^ ((r1 & 7) << 4)) >> 1]);
                #pragma unroll
                for (int ni = 0; ni < 2; ++ni) {
                    acc[mi][ni]     = mfma16(a0, bcur[ni], acc[mi][ni]);
                    acc[mi + 1][ni] = mfma16(a1, bcur[ni], acc[mi + 1][ni]);
                }
            }
            bcur[0] = bnxt[0]; bcur[1] = bnxt[1];
        }
    }
    __syncthreads();   // all h reads done -> safe to overwrite buf with feat

    // epilogue: +b2, relu, write feat into buf ([128][512] swizzled)
    #pragma unroll
    for (int ni = 0; ni < 2; ++ni) {
        int col = wid * 32 + ni * 16 + l15;
        float bias = b2[col];
        #pragma unroll
        for (int mi = 0; mi < 8; ++mi)
            #pragma unroll
            for (int r = 0; r < 4; ++r) {
                int row = mi * 16 + lk * 4 + r;
                float v = acc[mi][ni][r] + bias;
                v = v > 0.f ? v : 0.f;
                int byt = (row * 1024 + col * 2) ^ ((row & 7) << 4);
                buf[byt >> 1] = f2bf(v);
            }
    }
    __syncthreads();

    // ---------------- head1: g = relu(feat @ HW1[agent] + Hb1), N=32 ----------------
    // 16 waves: per agent of the pair, 4 row-quarters x 2 col-halves, full K=512.
    {
        const int ja  = wid >> 3;             // agent within pair
        const int sub = wid & 7;
        const int hm  = sub >> 1;             // row quarter 0..3
        const int hc  = sub & 1;              // col half 0..1
        const int a32 = ((2 * ap + ja) << 5);
        const unsigned short* hbase = HW1T + (size_t)(a32 + hc * 16 + l15) * 512 + lk * 8;
        f32x4 hacc = fzero;
        bf16x8 hb = *reinterpret_cast<const bf16x8*>(hbase);
        #pragma unroll 1
        for (int ks = 0; ks < 16; ++ks) {
            const int kn = (ks < 15 ? ks + 1 : 15);
            bf16x8 hn = *reinterpret_cast<const bf16x8*>(hbase + kn * 32);
            const int kk = ks * 32 + lk * 8;
            int row = ja * 64 + hm * 16 + l15;
            int byt = (row * 1024 + kk * 2) ^ ((row & 7) << 4);
            bf16x8 afh = *reinterpret_cast<const bf16x8*>(&buf[byt >> 1]);
            hacc = mfma16(afh, hb, hacc);
            hb = hn;
        }
        int col = hc * 16 + l15;
        float hbias = Hb1[a32 + col];
        #pragma unroll
        for (int r = 0; r < 4; ++r) {
            int row = ja * 64 + hm * 16 + lk * 4 + r;
            float v = hacc[r] + hbias;
            gpart[row * 36 + col] = v > 0.f ? v : 0.f;
        }
    }
    __syncthreads();

    // ---------------- head2: out = sigmoid(g . HW2[agent] + Hb2) ----------------
    if (tid < BROWS) {
        int e = tid & 63, j = tid >> 6;
        int a = 2 * ap + j;
        float x = Hb2[a];
        #pragma unroll 2
        for (int k = 0; k < 32; ++k)
            x += gpart[tid * 36 + k] * HW2[(a << 5) + k];
        out[(size_t)(e0 + e) * N_AGENTS + a] = 1.f / (1.f + expf(-x));
    }
}

extern "C" void kernel_launch(void* const* d_in, const int* in_sizes, int n_in,
                              void* d_out, int out_size, void* d_ws, size_t ws_size,
                              hipStream_t stream) {
    const float* obs = (const float*)d_in[0];
    const float* W1  = (const float*)d_in[1];
    const float* b1  = (const float*)d_in[2];
    const float* W2  = (const float*)d_in[3];
    const float* b2  = (const float*)d_in[4];
    const float* HW1 = (const float*)d_in[5];
    const float* Hb1 = (const float*)d_in[6];
    const float* HW2 = (const float*)d_in[7];
    const float* Hb2 = (const float*)d_in[8];
    float* out = (float*)d_out;

    unsigned short* W1T  = (unsigned short*)d_ws;     // 131072 elems
    unsigned short* W2T  = W1T + 131072;              // 262144 elems
    unsigned short* HW1T = W2T + 262144;              // 1048576 elems

    prep_weights_kernel<<<5632, 256, 0, stream>>>(W1, W2, HW1, W1T, W2T, HW1T);

    dim3 grid(N_ENVS / 64, N_AGENTS / 2);
    fused_mlp_kernel<<<grid, 1024, 0, stream>>>(obs, b1, b2, Hb1, HW2, Hb2,
                                                W1T, W2T, HW1T, out);
}

// Round 10
// 323.412 us; speedup vs baseline: 2.1118x; 2.1118x over previous
//
#include <hip/hip_runtime.h>
#include <hip/hip_bf16.h>
#include <math.h>

#define N_ENVS   4096
#define N_AGENTS 64
#define OBS_DIM  256
#define HIDDEN   512
#define HEADK    32
#define BROWS    128   // rows per block = 64 envs x 2 agents

typedef __attribute__((ext_vector_type(8))) short bf16x8;
typedef __attribute__((ext_vector_type(4))) float f32x4;

// HW packed f32x2 -> bf16x2 (RNE). One VALU op replaces ~8 for two elements.
static __device__ __forceinline__ unsigned cvt_pk_bf16(float lo, float hi) {
    unsigned r;
    asm("v_cvt_pk_bf16_f32 %0, %1, %2" : "=v"(r) : "v"(lo), "v"(hi));
    return r;
}

static __device__ __forceinline__ unsigned short f2bf(float x) {
    union { float f; unsigned int u; } v; v.f = x;
    unsigned int r = (v.u + 0x7FFFu + ((v.u >> 16) & 1u)) >> 16;
    return (unsigned short)r;
}

// Convert + transpose weights to bf16, N-major (so B-fragments are 16B contiguous).
__global__ void prep_weights_kernel(const float* __restrict__ W1,
                                    const float* __restrict__ W2,
                                    const float* __restrict__ HW1,
                                    unsigned short* __restrict__ W1T,
                                    unsigned short* __restrict__ W2T,
                                    unsigned short* __restrict__ HW1T) {
    int id = blockIdx.x * 256 + threadIdx.x;
    if (id < 131072) {                      // W1 [256][512] -> W1T [512][256]
        int k = id >> 9, n = id & 511;
        W1T[n * 256 + k] = f2bf(W1[id]);
    } else if (id < 131072 + 262144) {      // W2 [512][512] -> W2T [512][512]
        int t = id - 131072;
        int k = t >> 9, n = t & 511;
        W2T[n * 512 + k] = f2bf(W2[t]);
    } else if (id < 131072 + 262144 + 1048576) {  // HW1 [64][512][32] -> HW1T [64][32][512]
        int t = id - (131072 + 262144);
        int ag = t >> 14;
        int rem = t & 16383;
        int hh = rem >> 5, c = rem & 31;
        HW1T[((ag << 5) + c) * 512 + hh] = f2bf(HW1[t]);
    }
}

// Fused MLP. Block = 128 rows (64 envs x 2 agents), 1024 thr = 16 waves, each
// wave all 128 rows x 32 cols (acc[8][2] = 64 regs).
// Round-9 lesson: asm "+a" AGPR pinning forces a<->v copies -> 3x scratch. Use
// builtins. Round-10 change: OPERAND-SWAPPED MFMA mfma(W,A) gives transposed
// C-fragments (thread owns 1 row x 4 consecutive cols) so epilogues write
// ds_write_b64 (16/wave) instead of 64 scalar b16 -- the LDS-write pipe and
// its 4-way bank conflicts were ~20% of time. cvt_pk_bf16 halves epilogue and
// staging VALU. A/B MFMA operand layouts are symmetric -> swap is legal.
__launch_bounds__(1024, 1)
__global__ void fused_mlp_kernel(const float* __restrict__ obs,
                                 const float* __restrict__ b1,
                                 const float* __restrict__ b2,
                                 const float* __restrict__ Hb1,
                                 const float* __restrict__ HW2,
                                 const float* __restrict__ Hb2,
                                 const unsigned short* __restrict__ W1T,
                                 const unsigned short* __restrict__ W2T,
                                 const unsigned short* __restrict__ HW1T,
                                 float* __restrict__ out) {
    __shared__ unsigned short buf[BROWS * 512];  // 128 KB: obs(first half), h, feat
    __shared__ float gpart[BROWS * 36];          // 18 KB : g (pad 36)

    const int tid  = threadIdx.x;
    const int lane = tid & 63;
    const int wid  = tid >> 6;   // 0..15 : col group (32 cols each)
    const int l15  = lane & 15;
    const int lk   = lane >> 4;  // 0..3
    const int e0   = blockIdx.x * 64;
    const int ap   = blockIdx.y; // agent pair: agents 2ap, 2ap+1

    const f32x4 fzero = {0.f, 0.f, 0.f, 0.f};

    // ------------- stage obs tile [128][256] bf16 swizzled; row = j*64 + e -------------
    {
        const unsigned fbase = ((unsigned)e0 * 64u + 2u * (unsigned)ap) * 256u;
        #pragma unroll 1
        for (int g = 0; g < 4; ++g) {
            unsigned gi  = (unsigned)tid + 1024u * g;   // 4096 groups of 8 floats
            unsigned row = gi >> 5;                     // 0..127
            unsigned kg  = (gi & 31u) << 3;
            unsigned fidx = fbase + (row & 63u) * 16384u + (row >> 6) * 256u + kg;
            const float4* p = reinterpret_cast<const float4*>(obs + fidx);
            float4 v0 = p[0], v1 = p[1];
            uint4 w;
            w.x = cvt_pk_bf16(v0.x, v0.y);
            w.y = cvt_pk_bf16(v0.z, v0.w);
            w.z = cvt_pk_bf16(v1.x, v1.y);
            w.w = cvt_pk_bf16(v1.z, v1.w);
            unsigned byt = (row * 512u + kg * 2u) ^ ((row & 7u) << 4);
            *reinterpret_cast<uint4*>(&buf[byt >> 1]) = w;
        }
    }
    __syncthreads();

    // ---------------- GEMM1: h = relu(obs @ W1 + b1), K=256 ----------------
    f32x4 acc[8][2];   // transposed frags: [mi][ni], thread = row mi*16+l15, cols ni*16+lk*4+0..3
    #pragma unroll
    for (int i = 0; i < 8; ++i)
        #pragma unroll
        for (int j = 0; j < 2; ++j) acc[i][j] = fzero;

    {
        const unsigned short* bbase = W1T + (size_t)(wid * 32 + l15) * 256 + lk * 8;
        bf16x8 bcur[2];
        #pragma unroll
        for (int ni = 0; ni < 2; ++ni)
            bcur[ni] = *reinterpret_cast<const bf16x8*>(bbase + ni * 16 * 256);
        #pragma unroll 1
        for (int ks = 0; ks < 8; ++ks) {
            bf16x8 bnxt[2];
            const int kn = (ks < 7 ? ks + 1 : 7);
            #pragma unroll
            for (int ni = 0; ni < 2; ++ni)
                bnxt[ni] = *reinterpret_cast<const bf16x8*>(bbase + ni * 16 * 256 + kn * 32);
            const int kk = ks * 32 + lk * 8;
            #pragma unroll
            for (int mi = 0; mi < 8; ++mi) {
                int row = mi * 16 + l15;
                bf16x8 af = *reinterpret_cast<const bf16x8*>(&buf[((row * 512 + kk * 2) ^ ((row & 7) << 4)) >> 1]);
                #pragma unroll
                for (int ni = 0; ni < 2; ++ni)
                    acc[mi][ni] = __builtin_amdgcn_mfma_f32_16x16x32_bf16(bcur[ni], af, acc[mi][ni], 0, 0, 0);
            }
            bcur[0] = bnxt[0]; bcur[1] = bnxt[1];
        }
    }
    __syncthreads();   // all obs reads done -> safe to overwrite buf with h

    // epilogue: +b1, relu, packed b64 writes into buf ([128][512] swizzled)
    #pragma unroll
    for (int ni = 0; ni < 2; ++ni) {
        const int col0 = wid * 32 + ni * 16 + lk * 4;
        const float4 bias = *reinterpret_cast<const float4*>(b1 + col0);
        #pragma unroll
        for (int mi = 0; mi < 8; ++mi) {
            int row = mi * 16 + l15;
            float v0 = fmaxf(acc[mi][ni][0] + bias.x, 0.f);
            float v1 = fmaxf(acc[mi][ni][1] + bias.y, 0.f);
            float v2 = fmaxf(acc[mi][ni][2] + bias.z, 0.f);
            float v3 = fmaxf(acc[mi][ni][3] + bias.w, 0.f);
            uint2 w = { cvt_pk_bf16(v0, v1), cvt_pk_bf16(v2, v3) };
            int byt = (row * 1024 + col0 * 2) ^ ((row & 7) << 4);
            *reinterpret_cast<uint2*>(&buf[byt >> 1]) = w;
        }
    }
    __syncthreads();

    // ---------------- GEMM2: feat = relu(h @ W2 + b2), K=512 ----------------
    #pragma unroll
    for (int i = 0; i < 8; ++i)
        #pragma unroll
        for (int j = 0; j < 2; ++j) acc[i][j] = fzero;

    {
        const unsigned short* bbase = W2T + (size_t)(wid * 32 + l15) * 512 + lk * 8;
        bf16x8 bcur[2];
        #pragma unroll
        for (int ni = 0; ni < 2; ++ni)
            bcur[ni] = *reinterpret_cast<const bf16x8*>(bbase + ni * 16 * 512);
        #pragma unroll 1
        for (int ks = 0; ks < 16; ++ks) {
            bf16x8 bnxt[2];
            const int kn = (ks < 15 ? ks + 1 : 15);
            #pragma unroll
            for (int ni = 0; ni < 2; ++ni)
                bnxt[ni] = *reinterpret_cast<const bf16x8*>(bbase + ni * 16 * 512 + kn * 32);
            const int kk = ks * 32 + lk * 8;
            #pragma unroll
            for (int mi = 0; mi < 8; ++mi) {
                int row = mi * 16 + l15;
                bf16x8 af = *reinterpret_cast<const bf16x8*>(&buf[((row * 1024 + kk * 2) ^ ((row & 7) << 4)) >> 1]);
                #pragma unroll
                for (int ni = 0; ni < 2; ++ni)
                    acc[mi][ni] = __builtin_amdgcn_mfma_f32_16x16x32_bf16(bcur[ni], af, acc[mi][ni], 0, 0, 0);
            }
            bcur[0] = bnxt[0]; bcur[1] = bnxt[1];
        }
    }
    __syncthreads();   // all h reads done -> safe to overwrite buf with feat

    // epilogue: +b2, relu, packed b64 writes into buf ([128][512] swizzled)
    #pragma unroll
    for (int ni = 0; ni < 2; ++ni) {
        const int col0 = wid * 32 + ni * 16 + lk * 4;
        const float4 bias = *reinterpret_cast<const float4*>(b2 + col0);
        #pragma unroll
        for (int mi = 0; mi < 8; ++mi) {
            int row = mi * 16 + l15;
            float v0 = fmaxf(acc[mi][ni][0] + bias.x, 0.f);
            float v1 = fmaxf(acc[mi][ni][1] + bias.y, 0.f);
            float v2 = fmaxf(acc[mi][ni][2] + bias.z, 0.f);
            float v3 = fmaxf(acc[mi][ni][3] + bias.w, 0.f);
            uint2 w = { cvt_pk_bf16(v0, v1), cvt_pk_bf16(v2, v3) };
            int byt = (row * 1024 + col0 * 2) ^ ((row & 7) << 4);
            *reinterpret_cast<uint2*>(&buf[byt >> 1]) = w;
        }
    }
    __syncthreads();

    // ---------------- head1: g = relu(feat @ HW1[agent] + Hb1), N=32 ----------------
    // 16 waves: per agent of the pair, 4 row-quarters x 2 col-halves, full K=512.
    {
        const int ja  = wid >> 3;             // agent within pair
        const int sub = wid & 7;
        const int hm  = sub >> 1;             // row quarter 0..3
        const int hc  = sub & 1;              // col half 0..1
        const int a32 = ((2 * ap + ja) << 5);
        const unsigned short* hbase = HW1T + (size_t)(a32 + hc * 16 + l15) * 512 + lk * 8;
        f32x4 hacc = fzero;
        bf16x8 hb = *reinterpret_cast<const bf16x8*>(hbase);
        #pragma unroll 1
        for (int ks = 0; ks < 16; ++ks) {
            const int kn = (ks < 15 ? ks + 1 : 15);
            bf16x8 hn = *reinterpret_cast<const bf16x8*>(hbase + kn * 32);
            const int kk = ks * 32 + lk * 8;
            int row = ja * 64 + hm * 16 + l15;
            int byt = (row * 1024 + kk * 2) ^ ((row & 7) << 4);
            bf16x8 afh = *reinterpret_cast<const bf16x8*>(&buf[byt >> 1]);
            hacc = __builtin_amdgcn_mfma_f32_16x16x32_bf16(hb, afh, hacc, 0, 0, 0);
            hb = hn;
        }
        // transposed frag: thread owns feat-row ja*64+hm*16+l15, cols hc*16+lk*4+0..3
        const int col0 = hc * 16 + lk * 4;
        const float4 hbias = *reinterpret_cast<const float4*>(Hb1 + a32 + col0);
        int row = ja * 64 + hm * 16 + l15;
        float4 g;
        g.x = fmaxf(hacc[0] + hbias.x, 0.f);
        g.y = fmaxf(hacc[1] + hbias.y, 0.f);
        g.z = fmaxf(hacc[2] + hbias.z, 0.f);
        g.w = fmaxf(hacc[3] + hbias.w, 0.f);
        *reinterpret_cast<float4*>(&gpart[row * 36 + col0]) = g;
    }
    __syncthreads();

    // ---------------- head2: out = sigmoid(g . HW2[agent] + Hb2) ----------------
    if (tid < BROWS) {
        int e = tid & 63, j = tid >> 6;
        int a = 2 * ap + j;
        float x = Hb2[a];
        #pragma unroll 2
        for (int k = 0; k < 32; ++k)
            x += gpart[tid * 36 + k] * HW2[(a << 5) + k];
        out[(size_t)(e0 + e) * N_AGENTS + a] = 1.f / (1.f + expf(-x));
    }
}

extern "C" void kernel_launch(void* const* d_in, const int* in_sizes, int n_in,
                              void* d_out, int out_size, void* d_ws, size_t ws_size,
                              hipStream_t stream) {
    const float* obs = (const float*)d_in[0];
    const float* W1  = (const float*)d_in[1];
    const float* b1  = (const float*)d_in[2];
    const float* W2  = (const float*)d_in[3];
    const float* b2  = (const float*)d_in[4];
    const float* HW1 = (const float*)d_in[5];
    const float* Hb1 = (const float*)d_in[6];
    const float* HW2 = (const float*)d_in[7];
    const float* Hb2 = (const float*)d_in[8];
    float* out = (float*)d_out;

    unsigned short* W1T  = (unsigned short*)d_ws;     // 131072 elems
    unsigned short* W2T  = W1T + 131072;              // 262144 elems
    unsigned short* HW1T = W2T + 262144;              // 1048576 elems

    prep_weights_kernel<<<5632, 256, 0, stream>>>(W1, W2, HW1, W1T, W2T, HW1T);

    dim3 grid(N_ENVS / 64, N_AGENTS / 2);
    fused_mlp_kernel<<<grid, 1024, 0, stream>>>(obs, b1, b2, Hb1, HW2, Hb2,
                                                W1T, W2T, HW1T, out);
}